// Round 11
// baseline (589.646 us; speedup 1.0000x reference)
//
#include <hip/hip_runtime.h>

#define IN_CH 1024
#define INTER 512
#define NEXP  128
#define TPE   512

typedef __bf16 bf16x8  __attribute__((ext_vector_type(8)));
typedef __bf16 bf16x4v __attribute__((ext_vector_type(4)));
typedef float  f32x4   __attribute__((ext_vector_type(4)));

// Phase scaffolding (R5-proven at 2 blocks/CU).
#define PHASE_SYNC() do { \
  __builtin_amdgcn_s_barrier(); \
  asm volatile("s_waitcnt lgkmcnt(0)" ::: "memory"); \
  __builtin_amdgcn_sched_barrier(0); \
  __builtin_amdgcn_s_setprio(1); } while (0)
#define PHASE_END() do { \
  __builtin_amdgcn_s_setprio(0); \
  __builtin_amdgcn_s_barrier(); } while (0)

// ---------------- Kernel H: hX = x @ wX^T + bX  (X = 1 or 3, by sel bit) ----
// Exact moe_out machine balance (541 TF proven): BM=128 x BN=128, BK=64,
// 64 KB LDS dbuf, 2 blocks/CU, 2 phases/K-tile, NT=16. Both A (gathered x,
// fp32) and B (wX, fp32) staged with the proven fp32->bf16 pattern (swzB).
__global__ __launch_bounds__(512) void moe_hgemm_kernel(
    const float* __restrict__ x, const int* __restrict__ idxs,
    const float* __restrict__ w1w, const float* __restrict__ w1b,
    const float* __restrict__ w3w, const float* __restrict__ w3b,
    __bf16* __restrict__ h1buf, __bf16* __restrict__ h3buf)
{
  __shared__ __align__(16) ushort sA[2][128*64];
  __shared__ __align__(16) ushort sB[2][128*64];

  // XCD swizzle: 4096 blocks, 512/XCD; expert's 32 blocks (both gemms) on one XCD
  const int blk = (blockIdx.x & 7) * (NEXP*32/8) + (blockIdx.x >> 3);
  const int e   = blk >> 5;
  const int sel = (blk >> 4) & 1;           // 0 -> w1/h1, 1 -> w3/h3
  const int tl  = blk & 15;
  const int tm  = tl >> 2, tn = tl & 3;     // 4x4 tiles over 512x512

  const float* ww = sel ? w3w : w1w;
  const float* wb = sel ? w3b : w1b;
  __bf16*      hb = sel ? h3buf : h1buf;

  const int tid  = threadIdx.x;
  const int lane = tid & 63;
  const int wid  = tid >> 6;
  const int wm   = wid >> 1;       // 0..3
  const int wn   = wid & 1;        // 0..1

  // staging (both sides fp32): rows r0+32i (i<4), float4-col c4
  const int r0   = tid >> 4;          // 0..31
  const int c4   = tid & 15;          // 0..15
  const int swz  = ((((c4>>1) ^ (r0&7))<<3) | ((c4&1)<<2));

  const float* aptr[4];
#pragma unroll
  for (int i = 0; i < 4; ++i) {
    const int tok = idxs[e*TPE + tm*128 + r0 + 32*i];
    aptr[i] = x + (size_t)tok*IN_CH + (c4<<2);
  }
  const float* bp = ww + ((size_t)e*INTER + tn*128 + r0)*IN_CH + (c4<<2);

  f32x4 acc[2][4];
#pragma unroll
  for (int a = 0; a < 2; ++a)
#pragma unroll
    for (int b = 0; b < 4; ++b) acc[a][b] = (f32x4){0.f,0.f,0.f,0.f};

  float4 av[4], wv[4];

  auto loads = [&](int kof) {
#pragma unroll
    for (int i = 0; i < 4; ++i) {
      av[i] = *(const float4*)(aptr[i] + kof);
      wv[i] = *(const float4*)(bp + (size_t)(32*i)*IN_CH + kof);
    }
  };
  auto cvt4 = [](const float4& v) {
    bf16x4v b;
    b[0]=(__bf16)v.x; b[1]=(__bf16)v.y; b[2]=(__bf16)v.z; b[3]=(__bf16)v.w;
    return b;
  };
  auto stores = [&](int buf) {
#pragma unroll
    for (int i = 0; i < 4; ++i) {
      const int ro = (r0 + 32*i)*64 + swz;
      *(bf16x4v*)&sA[buf][ro] = cvt4(av[i]);
      *(bf16x4v*)&sB[buf][ro] = cvt4(wv[i]);
    }
  };
  auto rdA = [&](int buf, int ks, bf16x8 af[2]) {
    const int k8 = (ks<<2) + (lane>>4);
#pragma unroll
    for (int mi = 0; mi < 2; ++mi) {
      const int r = wm*32 + mi*16 + (lane&15);
      af[mi] = *(const bf16x8*)&sA[buf][r*64 + ((k8 ^ (r&7))<<3)];
    }
  };
  auto rdB = [&](int buf, int ks, bf16x8 bfr[4]) {
    const int k8 = (ks<<2) + (lane>>4);
#pragma unroll
    for (int ni = 0; ni < 4; ++ni) {
      const int r = wn*64 + ni*16 + (lane&15);
      bfr[ni] = *(const bf16x8*)&sB[buf][r*64 + ((k8 ^ (r&7))<<3)];
    }
  };

  loads(0);
  stores(0);
  loads(64);
  asm volatile("s_waitcnt lgkmcnt(0)" ::: "memory");
  __builtin_amdgcn_s_barrier();

  int cur = 0;
  const int NT = IN_CH/64;
  for (int kt = 0; kt < NT; ++kt) {
    bf16x8 af[2], bfr[4];

    // phase 0: ks=0 + cvt/ds_write of tile t+1
    rdA(cur, 0, af);
    rdB(cur, 0, bfr);
    if (kt < NT - 1) stores(cur ^ 1);
    PHASE_SYNC();
#pragma unroll
    for (int mi = 0; mi < 2; ++mi)
#pragma unroll
      for (int ni = 0; ni < 4; ++ni)
        acc[mi][ni] = __builtin_amdgcn_mfma_f32_16x16x32_bf16(af[mi], bfr[ni], acc[mi][ni], 0, 0, 0);
    PHASE_END();

    // phase 1: ks=1 + issue loads of tile t+2
    rdA(cur, 1, af);
    rdB(cur, 1, bfr);
    if (kt < NT - 2) loads((kt+2)*64);
    PHASE_SYNC();
#pragma unroll
    for (int mi = 0; mi < 2; ++mi)
#pragma unroll
      for (int ni = 0; ni < 4; ++ni)
        acc[mi][ni] = __builtin_amdgcn_mfma_f32_16x16x32_bf16(af[mi], bfr[ni], acc[mi][ni], 0, 0, 0);
    PHASE_END();

    cur ^= 1;
  }

  // epilogue: + bias, store bf16 hX tile (non-scattered, [e][tok][f])
  const int rowbase = tm*128 + wm*32;
  const int colbase = tn*128 + wn*64;
  float bv[4];
#pragma unroll
  for (int ni = 0; ni < 4; ++ni)
    bv[ni] = wb[e*INTER + colbase + ni*16 + (lane&15)];
#pragma unroll
  for (int mi = 0; mi < 2; ++mi) {
#pragma unroll
    for (int j = 0; j < 4; ++j) {
      const int rl = rowbase + mi*16 + ((lane>>4)<<2) + j;
      __bf16* hrow = hb + ((size_t)e*TPE + rl)*INTER;
#pragma unroll
      for (int ni = 0; ni < 4; ++ni)
        hrow[colbase + ni*16 + (lane&15)] = (__bf16)(acc[mi][ni][j] + bv[ni]);
    }
  }
}

// ---------------- Kernel B: out = (silu(h1)*h3) @ w2^T + b2, scattered ------
// R5-proven structure; A-staging fuses the SwiGLU combine (read h1,h3 chunks,
// silu*mul in fp32, pack bf16 -> sA).
__global__ __launch_bounds__(512) void moe_out_kernel(
    const __bf16* __restrict__ h1buf, const __bf16* __restrict__ h3buf,
    const float* __restrict__ w2w, const float* __restrict__ w2b,
    const int* __restrict__ idxs, float* __restrict__ out)
{
  __shared__ __align__(16) ushort sA[2][128*64];
  __shared__ __align__(16) ushort sB[2][128*64];

  const int blk = (blockIdx.x & 7) * (NEXP*32/8) + (blockIdx.x >> 3);
  const int e   = blk >> 5;
  const int tl  = blk & 31;
  const int tm  = tl >> 3, tn = tl & 7;

  const int tid  = threadIdx.x;
  const int lane = tid & 63;
  const int wid  = tid >> 6;
  const int wm   = wid >> 1;       // 0..3
  const int wn   = wid & 1;        // 0..1

  const int rA   = tid >> 3;          // 0..63
  const int c8   = tid & 7;           // 0..7
  const int swzA = ((c8 ^ (rA&7))<<3);
  const size_t aoff = ((size_t)e*TPE + tm*128 + rA)*INTER + (c8<<3);
  const __bf16* a1 = h1buf + aoff;
  const __bf16* a3 = h3buf + aoff;

  const int r0   = tid >> 4;          // 0..31
  const int c4   = tid & 15;
  const int swzB = ((((c4>>1) ^ (r0&7))<<3) | ((c4&1)<<2));
  const float* bp = w2w + ((size_t)e*IN_CH + tn*128 + r0)*INTER + (c4<<2);

  f32x4 acc[2][4];
#pragma unroll
  for (int a = 0; a < 2; ++a)
#pragma unroll
    for (int b = 0; b < 4; ++b) acc[a][b] = (f32x4){0.f,0.f,0.f,0.f};

  uint4  g1[2], g3[2];
  float4 wv[4];

  auto loads = [&](int kof) {
#pragma unroll
    for (int i = 0; i < 2; ++i) {
      g1[i] = *(const uint4*)(a1 + (size_t)(64*i)*INTER + kof);
      g3[i] = *(const uint4*)(a3 + (size_t)(64*i)*INTER + kof);
    }
#pragma unroll
    for (int i = 0; i < 4; ++i)
      wv[i] = *(const float4*)(bp + (size_t)(32*i)*INTER + kof);
  };
  auto stores = [&](int buf) {
#pragma unroll
    for (int i = 0; i < 2; ++i) {
      const bf16x8 v1 = *(const bf16x8*)&g1[i];
      const bf16x8 v3 = *(const bf16x8*)&g3[i];
      bf16x8 r;
#pragma unroll
      for (int j = 0; j < 8; ++j) {
        const float f1 = (float)v1[j];
        const float f3 = (float)v3[j];
        const float s  = f1 / (1.0f + __expf(-f1));
        r[j] = (__bf16)(s * f3);
      }
      *(bf16x8*)&sA[buf][(rA + 64*i)*64 + swzA] = r;
    }
#pragma unroll
    for (int i = 0; i < 4; ++i) {
      bf16x4v b;
      b[0]=(__bf16)wv[i].x; b[1]=(__bf16)wv[i].y; b[2]=(__bf16)wv[i].z; b[3]=(__bf16)wv[i].w;
      *(bf16x4v*)&sB[buf][(r0 + 32*i)*64 + swzB] = b;
    }
  };
  auto rdA = [&](int buf, int ks, bf16x8 af[2]) {
    const int k8 = (ks<<2) + (lane>>4);
#pragma unroll
    for (int mi = 0; mi < 2; ++mi) {
      const int r = wm*32 + mi*16 + (lane&15);
      af[mi] = *(const bf16x8*)&sA[buf][r*64 + ((k8 ^ (r&7))<<3)];
    }
  };
  auto rdB = [&](int buf, int ks, bf16x8 bfr[4]) {
    const int k8 = (ks<<2) + (lane>>4);
#pragma unroll
    for (int ni = 0; ni < 4; ++ni) {
      const int r = wn*64 + ni*16 + (lane&15);
      bfr[ni] = *(const bf16x8*)&sB[buf][r*64 + ((k8 ^ (r&7))<<3)];
    }
  };

  loads(0);
  stores(0);
  loads(64);
  asm volatile("s_waitcnt lgkmcnt(0)" ::: "memory");
  __builtin_amdgcn_s_barrier();

  int cur = 0;
  const int NT = INTER/64;
  for (int kt = 0; kt < NT; ++kt) {
    bf16x8 af[2], bfr[4];

    rdA(cur, 0, af);
    rdB(cur, 0, bfr);
    if (kt < NT - 1) stores(cur ^ 1);
    PHASE_SYNC();
#pragma unroll
    for (int mi = 0; mi < 2; ++mi)
#pragma unroll
      for (int ni = 0; ni < 4; ++ni)
        acc[mi][ni] = __builtin_amdgcn_mfma_f32_16x16x32_bf16(af[mi], bfr[ni], acc[mi][ni], 0, 0, 0);
    PHASE_END();

    rdA(cur, 1, af);
    rdB(cur, 1, bfr);
    if (kt < NT - 2) loads((kt+2)*64);
    PHASE_SYNC();
#pragma unroll
    for (int mi = 0; mi < 2; ++mi)
#pragma unroll
      for (int ni = 0; ni < 4; ++ni)
        acc[mi][ni] = __builtin_amdgcn_mfma_f32_16x16x32_bf16(af[mi], bfr[ni], acc[mi][ni], 0, 0, 0);
    PHASE_END();

    cur ^= 1;
  }

  const int rowbase = tm*128 + wm*32;
  const int colbase = tn*128 + wn*64;
  float b2v[4];
#pragma unroll
  for (int ni = 0; ni < 4; ++ni)
    b2v[ni] = w2b[e*IN_CH + colbase + ni*16 + (lane&15)];
#pragma unroll
  for (int mi = 0; mi < 2; ++mi) {
#pragma unroll
    for (int j = 0; j < 4; ++j) {
      const int rl  = rowbase + mi*16 + ((lane>>4)<<2) + j;
      const int tok = idxs[e*TPE + rl];
      float* orow = out + (size_t)tok*IN_CH;
#pragma unroll
      for (int ni = 0; ni < 4; ++ni)
        orow[colbase + ni*16 + (lane&15)] = acc[mi][ni][j] + b2v[ni];
    }
  }
}

extern "C" void kernel_launch(void* const* d_in, const int* in_sizes, int n_in,
                              void* d_out, int out_size, void* d_ws, size_t ws_size,
                              hipStream_t stream) {
  const float* x    = (const float*)d_in[0];
  const int*   idxs = (const int*)d_in[1];
  const float* w1w  = (const float*)d_in[2];
  const float* w1b  = (const float*)d_in[3];
  const float* w2w  = (const float*)d_in[4];
  const float* w2b  = (const float*)d_in[5];
  const float* w3w  = (const float*)d_in[6];
  const float* w3b  = (const float*)d_in[7];
  float*  out   = (float*)d_out;
  __bf16* h1buf = (__bf16*)d_ws;                      // 64 MB
  __bf16* h3buf = h1buf + (size_t)NEXP*TPE*INTER;     // +64 MB (ws >= 128 MB)

  moe_hgemm_kernel<<<dim3(NEXP*32), dim3(512), 0, stream>>>(
      x, idxs, w1w, w1b, w3w, w3b, h1buf, h3buf);
  moe_out_kernel<<<dim3(NEXP*32), dim3(512), 0, stream>>>(
      h1buf, h3buf, w2w, w2b, idxs, out);
}

// Round 12
// 490.186 us; speedup vs baseline: 1.2029x; 1.2029x over previous
//
#include <hip/hip_runtime.h>

#define IN_CH 1024
#define INTER 512
#define NEXP  128
#define TPE   512

typedef __bf16 bf16x8  __attribute__((ext_vector_type(8)));
typedef __bf16 bf16x4v __attribute__((ext_vector_type(4)));
typedef float  f32x4   __attribute__((ext_vector_type(4)));

// ISA-pinned staging load. "=&v" early-clobber keeps dst off the addr pair
// (R8 abort). asm volatile order pins issue before the barrier asm; dst
// liveness to stores() prevents sinking (R4/R6/R7 failure mode). Only safe
// when never spilled -> use at 1 blk/CU where VGPR budget is ~256 (R9 NaN
// was spill-under-128-cap).
#define GLOAD(dst, p) \
  asm volatile("global_load_dwordx4 %0, %1, off" : "=&v"(dst) : "v"(p))

// Wait staging loads then fence the scheduler (rule #18: register-only cvt
// hoists above inline-asm s_waitcnt despite "memory").
#define VM_WAIT() do { \
  asm volatile("s_waitcnt vmcnt(0)" ::: "memory"); \
  __builtin_amdgcn_sched_barrier(0); } while (0)

#define PHASE_SYNC() do { \
  __builtin_amdgcn_s_barrier(); \
  asm volatile("s_waitcnt lgkmcnt(0)" ::: "memory"); \
  __builtin_amdgcn_sched_barrier(0); \
  __builtin_amdgcn_s_setprio(1); } while (0)
#define PHASE_END() do { \
  __builtin_amdgcn_s_setprio(0); \
  __builtin_amdgcn_s_barrier(); } while (0)

// ---------------- Kernel A: h = silu(x@w1^T + b1) * (x@w3^T + b3) ------------
// R3 geometry: BM=BN=128, BK=64, 8 waves (4x2, wave=32 rows x 64 cols of
// BOTH gemms), dbuf 96 KB -> 1 blk/CU; 24 MFMAs per wave-K-step from 10
// fragment reads (best LDS economy measured). One barrier per K-step;
// asm-pinned loads(t+2) ride across it and land under MFMA(t).
__global__ __launch_bounds__(512) void moe_h_kernel(
    const float* __restrict__ x, const int* __restrict__ idxs,
    const float* __restrict__ w1w, const float* __restrict__ w1b,
    const float* __restrict__ w3w, const float* __restrict__ w3b,
    __bf16* __restrict__ hbuf)
{
  __shared__ __align__(16) ushort sA [2][128*64];
  __shared__ __align__(16) ushort sB1[2][128*64];
  __shared__ __align__(16) ushort sB3[2][128*64];   // 96 KB

  // XCD swizzle: 2048 blocks, 256/XCD
  const int blk = (blockIdx.x & 7) * (NEXP*16/8) + (blockIdx.x >> 3);
  const int e   = blk >> 4;
  const int tl  = blk & 15;
  const int tm  = tl >> 2, tn = tl & 3;

  const int tid  = threadIdx.x;
  const int lane = tid & 63;
  const int wid  = tid >> 6;
  const int wm   = wid >> 1;       // 0..3 -> 32-row slice
  const int wn   = wid & 1;        // 0..1 -> 64-col slice

  const int r0 = tid >> 4;   // 0..31
  const int c4 = tid & 15;   // 0..15

  const float* aptr[4];
#pragma unroll
  for (int i = 0; i < 4; ++i) {
    const int tok = idxs[e*TPE + tm*128 + r0 + 32*i];
    aptr[i] = x + (size_t)tok*IN_CH + (c4<<2);
  }
  const float* b1p = w1w + ((size_t)e*INTER + tn*128 + r0)*IN_CH + (c4<<2);
  const float* b3p = w3w + ((size_t)e*INTER + tn*128 + r0)*IN_CH + (c4<<2);

  const int swz = ((((c4>>1) ^ (r0&7))<<3) | ((c4&1)<<2));

  f32x4 acc1[2][4], acc3[2][4];
#pragma unroll
  for (int a = 0; a < 2; ++a)
#pragma unroll
    for (int b = 0; b < 4; ++b) {
      acc1[a][b] = (f32x4){0.f,0.f,0.f,0.f};
      acc3[a][b] = (f32x4){0.f,0.f,0.f,0.f};
    }

  f32x4 xv[4], v1[4], v3[4];   // 48 staging VGPRs, asm-pinned

  auto loads = [&](int kof) {
#pragma unroll
    for (int i = 0; i < 4; ++i) {
      GLOAD(xv[i], aptr[i] + kof);
      GLOAD(v1[i], b1p + (size_t)(32*i)*IN_CH + kof);
      GLOAD(v3[i], b3p + (size_t)(32*i)*IN_CH + kof);
    }
  };
  auto cvt4 = [](const f32x4& v) {
    bf16x4v b;
    b[0]=(__bf16)v[0]; b[1]=(__bf16)v[1]; b[2]=(__bf16)v[2]; b[3]=(__bf16)v[3];
    return b;
  };
  auto stores = [&](int buf) {
    VM_WAIT();
#pragma unroll
    for (int i = 0; i < 4; ++i) {
      const int ro = (r0 + 32*i)*64 + swz;
      *(bf16x4v*)&sA [buf][ro] = cvt4(xv[i]);
      *(bf16x4v*)&sB1[buf][ro] = cvt4(v1[i]);
      *(bf16x4v*)&sB3[buf][ro] = cvt4(v3[i]);
    }
  };
  auto mfma_tile = [&](int buf) {
#pragma unroll
    for (int ks = 0; ks < 2; ++ks) {
      bf16x8 af[2], bq[4], bt[4];
      const int k8 = (ks<<2) + (lane>>4);
#pragma unroll
      for (int mi = 0; mi < 2; ++mi) {
        const int r = wm*32 + mi*16 + (lane&15);
        af[mi] = *(const bf16x8*)&sA[buf][r*64 + ((k8 ^ (r&7))<<3)];
      }
#pragma unroll
      for (int ni = 0; ni < 4; ++ni) {
        const int r   = wn*64 + ni*16 + (lane&15);
        const int off = r*64 + ((k8 ^ (r&7))<<3);
        bq[ni] = *(const bf16x8*)&sB1[buf][off];
        bt[ni] = *(const bf16x8*)&sB3[buf][off];
      }
#pragma unroll
      for (int mi = 0; mi < 2; ++mi)
#pragma unroll
        for (int ni = 0; ni < 4; ++ni) {
          acc1[mi][ni] = __builtin_amdgcn_mfma_f32_16x16x32_bf16(af[mi], bq[ni], acc1[mi][ni], 0, 0, 0);
          acc3[mi][ni] = __builtin_amdgcn_mfma_f32_16x16x32_bf16(af[mi], bt[ni], acc3[mi][ni], 0, 0, 0);
        }
    }
  };

  // prologue: tile0 staged, tile1 in flight
  loads(0);
  stores(0);
  loads(64);
  asm volatile("s_waitcnt lgkmcnt(0)" ::: "memory");
  __builtin_amdgcn_s_barrier();

  int cur = 0;
  const int NT = IN_CH/64;
  for (int kt = 0; kt < NT; ++kt) {
    if (kt < NT - 1) stores(cur ^ 1);        // vmcnt waits tile t+1 (landed under prev MFMA)
    if (kt < NT - 2) loads((kt+2)*64);       // t+2 rides across barrier + MFMA
    __builtin_amdgcn_s_setprio(1);
    mfma_tile(cur);
    __builtin_amdgcn_s_setprio(0);
    asm volatile("s_waitcnt lgkmcnt(0)" ::: "memory");
    __builtin_amdgcn_s_barrier();
    cur ^= 1;
  }

  // epilogue: bias + SwiGLU, store bf16 h tile
  const int rowbase = tm*128 + wm*32;
  const int colbase = tn*128 + wn*64;
#pragma unroll
  for (int ni = 0; ni < 4; ++ni) {
    const int fc = colbase + ni*16 + (lane&15);
    const float b1v = w1b[e*INTER + fc];
    const float b3v = w3b[e*INTER + fc];
#pragma unroll
    for (int mi = 0; mi < 2; ++mi) {
#pragma unroll
      for (int j = 0; j < 4; ++j) {
        const int rl = rowbase + mi*16 + ((lane>>4)<<2) + j;
        const float h1 = acc1[mi][ni][j] + b1v;
        const float h3 = acc3[mi][ni][j] + b3v;
        const float s  = h1 / (1.0f + __expf(-h1));
        hbuf[((size_t)e*TPE + rl)*INTER + fc] = (__bf16)(s * h3);
      }
    }
  }
}

// ---------------- Kernel B: out = h @ w2^T + b2, scattered via idxs ----------
// R5/R10-verbatim (plain HIP, 2 blocks/CU, 2 phases/K-tile, ~136 us).
__global__ __launch_bounds__(512) void moe_out_kernel(
    const __bf16* __restrict__ hbuf, const float* __restrict__ w2w,
    const float* __restrict__ w2b, const int* __restrict__ idxs,
    float* __restrict__ out)
{
  __shared__ __align__(16) ushort sA[2][128*64];
  __shared__ __align__(16) ushort sB[2][128*64];

  const int blk = (blockIdx.x & 7) * (NEXP*32/8) + (blockIdx.x >> 3);
  const int e   = blk >> 5;
  const int tl  = blk & 31;
  const int tm  = tl >> 3, tn = tl & 7;

  const int tid  = threadIdx.x;
  const int lane = tid & 63;
  const int wid  = tid >> 6;
  const int wm   = wid >> 1;       // 0..3
  const int wn   = wid & 1;        // 0..1

  const int rA   = tid >> 3;          // 0..63
  const int c8   = tid & 7;           // 0..7
  const int swzA = ((c8 ^ (rA&7))<<3);
  const __bf16* ap = hbuf + ((size_t)e*TPE + tm*128 + rA)*INTER + (c8<<3);

  const int r0   = tid >> 4;          // 0..31
  const int c4   = tid & 15;
  const int swzB = ((((c4>>1) ^ (r0&7))<<3) | ((c4&1)<<2));
  const float* bp = w2w + ((size_t)e*IN_CH + tn*128 + r0)*INTER + (c4<<2);

  f32x4 acc[2][4];
#pragma unroll
  for (int a = 0; a < 2; ++a)
#pragma unroll
    for (int b = 0; b < 4; ++b) acc[a][b] = (f32x4){0.f,0.f,0.f,0.f};

  uint4  hv[2];
  float4 wv[4];

  auto loads = [&](int kof) {
#pragma unroll
    for (int i = 0; i < 2; ++i)
      hv[i] = *(const uint4*)(ap + (size_t)(64*i)*INTER + kof);
#pragma unroll
    for (int i = 0; i < 4; ++i)
      wv[i] = *(const float4*)(bp + (size_t)(32*i)*INTER + kof);
  };
  auto stores = [&](int buf) {
#pragma unroll
    for (int i = 0; i < 2; ++i)
      *(uint4*)&sA[buf][(rA + 64*i)*64 + swzA] = hv[i];
#pragma unroll
    for (int i = 0; i < 4; ++i) {
      bf16x4v b;
      b[0]=(__bf16)wv[i].x; b[1]=(__bf16)wv[i].y; b[2]=(__bf16)wv[i].z; b[3]=(__bf16)wv[i].w;
      *(bf16x4v*)&sB[buf][(r0 + 32*i)*64 + swzB] = b;
    }
  };
  auto rdA = [&](int buf, int ks, bf16x8 af[2]) {
    const int k8 = (ks<<2) + (lane>>4);
#pragma unroll
    for (int mi = 0; mi < 2; ++mi) {
      const int r = wm*32 + mi*16 + (lane&15);
      af[mi] = *(const bf16x8*)&sA[buf][r*64 + ((k8 ^ (r&7))<<3)];
    }
  };
  auto rdB = [&](int buf, int ks, bf16x8 bfr[4]) {
    const int k8 = (ks<<2) + (lane>>4);
#pragma unroll
    for (int ni = 0; ni < 4; ++ni) {
      const int r = wn*64 + ni*16 + (lane&15);
      bfr[ni] = *(const bf16x8*)&sB[buf][r*64 + ((k8 ^ (r&7))<<3)];
    }
  };

  loads(0);
  stores(0);
  loads(64);
  asm volatile("s_waitcnt lgkmcnt(0)" ::: "memory");
  __builtin_amdgcn_s_barrier();

  int cur = 0;
  const int NT = INTER/64;
  for (int kt = 0; kt < NT; ++kt) {
    bf16x8 af[2], bfr[4];

    rdA(cur, 0, af);
    rdB(cur, 0, bfr);
    if (kt < NT - 1) stores(cur ^ 1);
    PHASE_SYNC();
#pragma unroll
    for (int mi = 0; mi < 2; ++mi)
#pragma unroll
      for (int ni = 0; ni < 4; ++ni)
        acc[mi][ni] = __builtin_amdgcn_mfma_f32_16x16x32_bf16(af[mi], bfr[ni], acc[mi][ni], 0, 0, 0);
    PHASE_END();

    rdA(cur, 1, af);
    rdB(cur, 1, bfr);
    if (kt < NT - 2) loads((kt+2)*64);
    PHASE_SYNC();
#pragma unroll
    for (int mi = 0; mi < 2; ++mi)
#pragma unroll
      for (int ni = 0; ni < 4; ++ni)
        acc[mi][ni] = __builtin_amdgcn_mfma_f32_16x16x32_bf16(af[mi], bfr[ni], acc[mi][ni], 0, 0, 0);
    PHASE_END();

    cur ^= 1;
  }

  const int rowbase = tm*128 + wm*32;
  const int colbase = tn*128 + wn*64;
  float b2v[4];
#pragma unroll
  for (int ni = 0; ni < 4; ++ni)
    b2v[ni] = w2b[e*IN_CH + colbase + ni*16 + (lane&15)];
#pragma unroll
  for (int mi = 0; mi < 2; ++mi) {
#pragma unroll
    for (int j = 0; j < 4; ++j) {
      const int rl  = rowbase + mi*16 + ((lane>>4)<<2) + j;
      const int tok = idxs[e*TPE + rl];
      float* orow = out + (size_t)tok*IN_CH;
#pragma unroll
      for (int ni = 0; ni < 4; ++ni)
        orow[colbase + ni*16 + (lane&15)] = acc[mi][ni][j] + b2v[ni];
    }
  }
}

extern "C" void kernel_launch(void* const* d_in, const int* in_sizes, int n_in,
                              void* d_out, int out_size, void* d_ws, size_t ws_size,
                              hipStream_t stream) {
  const float* x    = (const float*)d_in[0];
  const int*   idxs = (const int*)d_in[1];
  const float* w1w  = (const float*)d_in[2];
  const float* w1b  = (const float*)d_in[3];
  const float* w2w  = (const float*)d_in[4];
  const float* w2b  = (const float*)d_in[5];
  const float* w3w  = (const float*)d_in[6];
  const float* w3b  = (const float*)d_in[7];
  float*  out  = (float*)d_out;
  __bf16* hbuf = (__bf16*)d_ws;   // 128*512*512 bf16 = 64 MB intermediate

  moe_h_kernel<<<dim3(NEXP*16), dim3(512), 0, stream>>>(x, idxs, w1w, w1b, w3w, w3b, hbuf);
  moe_out_kernel<<<dim3(NEXP*32), dim3(512), 0, stream>>>(hbuf, w2w, w2b, idxs, out);
}